// Round 5
// baseline (1834.107 us; speedup 1.0000x reference)
//
#include <hip/hip_runtime.h>

typedef _Float16 f16;
typedef _Float16 f16x8 __attribute__((ext_vector_type(8)));
typedef float floatx4 __attribute__((ext_vector_type(4)));

#define NBLK 512

__device__ __forceinline__ float ftanh(float x) {
  float ax = __builtin_fabsf(x);
  float e  = __expf(-2.0f * ax);
  float t  = (1.0f - e) * __builtin_amdgcn_rcpf(1.0f + e);
  return x < 0.0f ? -t : t;
}

// async global->LDS, 16B/lane; LDS base wave-uniform, HW scatters lane i to base+i*16.
__device__ __forceinline__ void gll16(const f16* g, f16* l) {
  __builtin_amdgcn_global_load_lds(
      (const __attribute__((address_space(1))) void*)g,
      (__attribute__((address_space(3))) void*)l, 16, 0, 0);
}

// Device-scope grid barrier (G16): RELEASE arrival flushes this XCD's dirty L2
// to the coherent point; ACQUIRE fence after spin invalidates L1/L2 so plain
// loads see other XCDs' data. Spin uses relaxed atomic loads (coherent-point
// reads, no repeated invalidates). Guarded: a residency failure exits after
// ~0.3s instead of hanging the harness.
__device__ __forceinline__ void gridbar(unsigned* cnt, unsigned target) {
  __syncthreads();   // all block lanes done (compiler drains vmcnt before s_barrier)
  if (threadIdx.x == 0) {
    __hip_atomic_fetch_add(cnt, 1u, __ATOMIC_RELEASE, __HIP_MEMORY_SCOPE_AGENT);
    int guard = 0;
    while (__hip_atomic_load(cnt, __ATOMIC_RELAXED, __HIP_MEMORY_SCOPE_AGENT) < target
           && ++guard < (1 << 21))
      __builtin_amdgcn_s_sleep(4);
    __builtin_amdgcn_fence(__ATOMIC_ACQUIRE, "agent");
  }
  __syncthreads();
}

// 128 x (FJ*32) tile GEMM step: A split at k=512 between two sources,
// W [N][K] k-contiguous, bias+tanh epilogue via LDS transpose, out stride 512.
template<int FJ>
__device__ __forceinline__ void tile_gemm(
    const f16* __restrict__ A0, int ldA0,   // k in [0,512)
    const f16* __restrict__ A1, int ldA1,   // k in [512,K), col index k-512
    int K, const f16* __restrict__ WT,
    const float* __restrict__ bias,
    f16* __restrict__ outp, int bm, int bn, f16* sm)
{
  const int tid  = threadIdx.x;
  const int w    = tid >> 6;
  const int lane = tid & 63;
  const int lm   = lane & 15;
  const int quad = lane >> 4;
  const int wm   = (w >> 1) * 64;
  const int wn   = (w & 1) * (FJ * 16);
  const int srow8 = lane >> 3;
  const int scol  = (lane & 7) * 8;

  f16* As0 = sm;
  f16* Ws0 = sm + 128 * 64;

  floatx4 acc[4][FJ];
  #pragma unroll
  for (int i = 0; i < 4; ++i)
    #pragma unroll
    for (int j = 0; j < FJ; ++j)
      acc[i][j] = (floatx4){0.f, 0.f, 0.f, 0.f};

  for (int k0 = 0; k0 < K; k0 += 64) {
    const f16* Asrc = (k0 < 512) ? (A0 + k0) : (A1 + (k0 - 512));
    const int  ld   = (k0 < 512) ? ldA0 : ldA1;
    #pragma unroll
    for (int i = 0; i < 4; ++i) {
      int r = (w * 4 + i) * 8 + srow8;
      gll16(Asrc + (size_t)(bm + r) * ld + scol, As0 + (w * 4 + i) * 512);
    }
    #pragma unroll
    for (int i = 0; i < FJ; ++i) {
      int r = (w * FJ + i) * 8 + srow8;
      gll16(WT + (size_t)(bn + r) * K + k0 + scol, Ws0 + (w * FJ + i) * 512);
    }
    __syncthreads();
    #pragma unroll
    for (int kk = 0; kk < 64; kk += 32) {
      f16x8 a[4], bfr[FJ];
      #pragma unroll
      for (int fi = 0; fi < 4; ++fi)
        a[fi] = *(const f16x8*)&As0[(size_t)(wm + fi * 16 + lm) * 64 + kk + quad * 8];
      #pragma unroll
      for (int fj = 0; fj < FJ; ++fj)
        bfr[fj] = *(const f16x8*)&Ws0[(size_t)(wn + fj * 16 + lm) * 64 + kk + quad * 8];
      #pragma unroll
      for (int fi = 0; fi < 4; ++fi)
        #pragma unroll
        for (int fj = 0; fj < FJ; ++fj)
          acc[fi][fj] = __builtin_amdgcn_mfma_f32_16x16x32_f16(a[fi], bfr[fj], acc[fi][fj], 0, 0, 0);
    }
    __syncthreads();
  }

  // epilogue: C/D layout col=lane&15, row=quad*4+reg [m89/m91] -> LDS transpose
  constexpr int ES = FJ * 32 + 8;
  #pragma unroll
  for (int fi = 0; fi < 4; ++fi)
    #pragma unroll
    for (int fj = 0; fj < FJ; ++fj) {
      int col = wn + fj * 16 + lm;
      #pragma unroll
      for (int r = 0; r < 4; ++r) {
        int row = wm + fi * 16 + quad * 4 + r;
        sm[row * ES + col] = (f16)acc[fi][fj][r];
      }
    }
  __syncthreads();
  constexpr int TPR = (FJ * 32) / 8;     // threads per row
  constexpr int RPP = 256 / TPR;         // rows per pass
  #pragma unroll
  for (int p = 0; p < 128 / RPP; ++p) {
    int row = p * RPP + tid / TPR;
    int c8  = (tid % TPR) * 8;
    f16x8 ve = *(const f16x8*)&sm[row * ES + c8];
    floatx4 bv0 = *(const floatx4*)&bias[bn + c8];
    floatx4 bv1 = *(const floatx4*)&bias[bn + c8 + 4];
    union { f16 e[8]; f16x8 v; } o;
    #pragma unroll
    for (int j = 0; j < 4; ++j) o.e[j]     = (f16)ftanh((float)ve[j]     + bv0[j]);
    #pragma unroll
    for (int j = 0; j < 4; ++j) o.e[4 + j] = (f16)ftanh((float)ve[4 + j] + bv1[j]);
    *(f16x8*)(outp + (size_t)(bm + row) * 512 + bn + c8) = o.v;
  }
}

// ---------------------------------------------------------------------------
// ONE persistent kernel: prep -> 22 RNN wavefronts (grid barriers) -> FC.
// 512 blocks @ __launch_bounds__(256,2): residency provable (LDS 34816B -> 4/CU
// cap, VGPR<=256). Layer z0: 256 blocks, tile 128x64, K=832 ([h0 | x_t] vs
// [wh0 ; W_emb*wx0] -- u0 GEMM folded in). z1/z2: 128 blocks each, 128x128,
// K=1024. bm-slab <-> XCD fixed across layers: H traffic stays on-XCD.
// ---------------------------------------------------------------------------
__global__ __launch_bounds__(256, 2)
void rnn_all(const float* __restrict__ x,
             const float* __restrict__ W_emb, const float* __restrict__ b_emb,
             const float* __restrict__ wx0, const float* __restrict__ wh0,
             const float* __restrict__ b0,
             const float* __restrict__ wx1, const float* __restrict__ wh1,
             const float* __restrict__ b1,
             const float* __restrict__ wx2, const float* __restrict__ wh2,
             const float* __restrict__ b2,
             const float* __restrict__ W_fc, const float* __restrict__ b_fc,
             f16* __restrict__ xh, f16* __restrict__ W0T, f16* __restrict__ W1T,
             f16* __restrict__ W2T, float* __restrict__ bcomb,
             f16* H0a, f16* H0b, f16* H1a, f16* H1b, f16* H2a, f16* H2b,
             float* __restrict__ out, unsigned* __restrict__ cnt)
{
  __shared__ f16 sm[17408];   // 34816 B: max(staging 128x64+128x64, epi 128x136)
  const int b   = blockIdx.x;
  const int tid = threadIdx.x;
  const int gid = b * 256 + tid;

  // ---------------- prep phase ----------------
  if (b < 352) {
    // x [81920][300] fp32 -> xh [81920][320] f16 (zero-padded)
    for (int U = gid; U < 3276800; U += 352 * 256) {
      int row = U / 40;
      int c   = (U - row * 40) * 8;
      union { f16 e[8]; f16x8 v; } t;
      const float* src = x + (size_t)row * 300 + c;
      if (c + 8 <= 300) {
        floatx4 v0 = *(const floatx4*)src, v1 = *(const floatx4*)(src + 4);
        #pragma unroll
        for (int j = 0; j < 4; ++j) { t.e[j] = (f16)v0[j]; t.e[4 + j] = (f16)v1[j]; }
      } else if (c < 300) {   // c == 296: 4 real + 4 pad
        floatx4 v0 = *(const floatx4*)src;
        #pragma unroll
        for (int j = 0; j < 4; ++j) { t.e[j] = (f16)v0[j]; t.e[4 + j] = (f16)0.f; }
      } else {
        #pragma unroll
        for (int j = 0; j < 8; ++j) t.e[j] = (f16)0.f;
      }
      *(f16x8*)(xh + (size_t)row * 320 + c) = t.v;
    }
  } else if (b < 448) {
    // Wce = W_emb @ wx0 into W0T[:, 512+k] (k<320, zero pad past 300)
    for (int i = gid - 352 * 256; i < 163840; i += 96 * 256) {
      int n = i & 511, k = i >> 9;
      float s = 0.f;
      if (k < 300) {
        #pragma unroll 4
        for (int j = 0; j < 512; ++j)
          s = __builtin_fmaf(W_emb[k * 512 + j], wx0[j * 512 + n], s);
      }
      W0T[(size_t)n * 832 + 512 + k] = (f16)s;
    }
    if (b == 447) {   // bcomb = b0 + b_emb @ wx0
      for (int n = tid; n < 512; n += 256) {
        float s = b0[n];
        for (int j = 0; j < 512; ++j)
          s = __builtin_fmaf(b_emb[j], wx0[j * 512 + n], s);
        bcomb[n] = s;
      }
    }
  } else if (b < 472) {
    // weight transposes: wh0 -> W0T[:, :512]; [wx1;wh1] -> W1T; [wx2;wh2] -> W2T
    for (int i = (b - 448) * 256 + tid; i < 1310720; i += 24 * 256) {
      if (i < 262144) {
        int n = i & 511, k = i >> 9;
        W0T[(size_t)n * 832 + k] = (f16)wh0[k * 512 + n];
      } else if (i < 786432) {
        int i2 = i - 262144;
        int n = i2 & 511, k = i2 >> 9;
        float v = (k < 512) ? wx1[k * 512 + n] : wh1[(k - 512) * 512 + n];
        W1T[(size_t)n * 1024 + k] = (f16)v;
      } else {
        int i2 = i - 786432;
        int n = i2 & 511, k = i2 >> 9;
        float v = (k < 512) ? wx2[k * 512 + n] : wh2[(k - 512) * 512 + n];
        W2T[(size_t)n * 1024 + k] = (f16)v;
      }
    }
  } else {
    // zero-init h(-1) buffers: H0a, H1b, H2a (3 x 2097152 f16 = 786432 x f16x8)
    f16x8 z8 = {};
    for (int i = (b - 472) * 256 + tid; i < 786432; i += 40 * 256) {
      f16* dst = (i < 262144) ? H0a : (i < 524288) ? H1b : H2a;
      *(f16x8*)(dst + (size_t)(i & 262143) * 8) = z8;
    }
  }

  unsigned epoch = 0;
  gridbar(cnt, ++epoch * NBLK);

  // ---------------- 22 anti-diagonal wavefronts ----------------
  const int xcd  = b & 7;
  const int q    = b >> 3;                // 0..63
  const int slab = xcd + 8 * (q & 3);     // 0..31, slab<->XCD fixed for all z
  const int role = q >> 2;                // 0..15: 0-7 z0, 8-11 z1, 12-15 z2
  const int bm   = slab * 128;

  for (int wv = 0; wv < 22; ++wv) {
    const int cur = wv & 1;
    f16* H0c = cur ? H0b : H0a;  f16* H0n = cur ? H0a : H0b;
    f16* H1c = cur ? H1b : H1a;  f16* H1n = cur ? H1a : H1b;
    f16* H2c = cur ? H2b : H2a;  f16* H2n = cur ? H2a : H2b;

    if (role < 8) {
      // z0, t=wv: h0 = tanh([h0(t-1) | x_t] @ [wh0 ; Wce] + bcomb)
      if (wv <= 19)
        tile_gemm<2>(H0c, 512, xh + (size_t)wv * 320, 6400, 832, W0T, bcomb,
                     H0n, bm, role * 64, sm);
    } else if (role < 12) {
      // z1, t=wv-1: h1 = tanh([h0(t) | h1(t-1)] @ [wx1;wh1] + b1)
      if (wv >= 1 && wv <= 20)
        tile_gemm<4>(H0c, 512, H1c, 512, 1024, W1T, b1,
                     H1n, bm, (role - 8) * 128, sm);
    } else {
      // z2, t=wv-2: h2 = tanh([h1(t) | h2(t-1)] @ [wx2;wh2] + b2)
      if (wv >= 2)
        tile_gemm<4>(H1c, 512, H2c, 512, 1024, W2T, b2,
                     H2n, bm, (role - 12) * 128, sm);
    }
    gridbar(cnt, ++epoch * NBLK);
  }

  // ---------------- FC tail: out = h2(19) @ W_fc + b_fc ----------------
  // h2(19) written at wv=21 into H2n(cur=1) = H2a.
  if (b < 160) {
    int id  = gid;                 // 0..40959
    int row = id / 10;
    int c   = id - row * 10;
    float s = b_fc[c];
    const f16* hr = H2a + (size_t)row * 512;
    for (int k8 = 0; k8 < 64; ++k8) {
      f16x8 h8 = *(const f16x8*)(hr + k8 * 8);
      #pragma unroll
      for (int j = 0; j < 8; ++j)
        s = __builtin_fmaf((float)h8[j], W_fc[(k8 * 8 + j) * 10 + c], s);
    }
    out[id] = s;
  }
}

extern "C" void kernel_launch(void* const* d_in, const int* in_sizes, int n_in,
                              void* d_out, int out_size, void* d_ws, size_t ws_size,
                              hipStream_t stream)
{
  (void)in_sizes; (void)n_in; (void)out_size; (void)ws_size;
  const float* x     = (const float*)d_in[0];
  const float* W_emb = (const float*)d_in[1];
  const float* b_emb = (const float*)d_in[2];
  const float* wx0   = (const float*)d_in[3];
  const float* wh0   = (const float*)d_in[4];
  const float* b0    = (const float*)d_in[5];
  const float* wx1   = (const float*)d_in[6];
  const float* wh1   = (const float*)d_in[7];
  const float* b1    = (const float*)d_in[8];
  const float* wx2   = (const float*)d_in[9];
  const float* wh2   = (const float*)d_in[10];
  const float* b2    = (const float*)d_in[11];
  const float* W_fc  = (const float*)d_in[12];
  const float* b_fc  = (const float*)d_in[13];
  float* out = (float*)d_out;

  char* ws = (char*)d_ws;
  size_t off = 0;
  auto alloc = [&](size_t bytes) -> void* {
    void* p = ws + off;
    off = (off + bytes + 255) & ~(size_t)255;
    return p;
  };
  f16*      xh    = (f16*)alloc((size_t)81920 * 320 * 2);   // 52.4 MB
  f16*      W0T   = (f16*)alloc((size_t)512 * 832 * 2);
  f16*      W1T   = (f16*)alloc((size_t)512 * 1024 * 2);
  f16*      W2T   = (f16*)alloc((size_t)512 * 1024 * 2);
  float*    bcomb = (float*)alloc(512 * 4);
  f16*      H0a   = (f16*)alloc((size_t)4096 * 512 * 2);
  f16*      H0b   = (f16*)alloc((size_t)4096 * 512 * 2);
  f16*      H1a   = (f16*)alloc((size_t)4096 * 512 * 2);
  f16*      H1b   = (f16*)alloc((size_t)4096 * 512 * 2);
  f16*      H2a   = (f16*)alloc((size_t)4096 * 512 * 2);
  f16*      H2b   = (f16*)alloc((size_t)4096 * 512 * 2);
  unsigned* cnt   = (unsigned*)alloc(256);

  hipMemsetAsync(cnt, 0, 256, stream);
  rnn_all<<<512, 256, 0, stream>>>(
      x, W_emb, b_emb, wx0, wh0, b0, wx1, wh1, b1, wx2, wh2, b2, W_fc, b_fc,
      xh, W0T, W1T, W2T, bcomb, H0a, H0b, H1a, H1b, H2a, H2b, out, cnt);
}

// Round 7
// 857.219 us; speedup vs baseline: 2.1396x; 2.1396x over previous
//
#include <hip/hip_runtime.h>

typedef _Float16 f16;
typedef _Float16 f16x8 __attribute__((ext_vector_type(8)));
typedef float floatx4 __attribute__((ext_vector_type(4)));

__device__ __forceinline__ float ftanh(float x) {
  float ax = __builtin_fabsf(x);
  float e  = __expf(-2.0f * ax);
  float t  = (1.0f - e) * __builtin_amdgcn_rcpf(1.0f + e);
  return x < 0.0f ? -t : t;
}

// async global->LDS, 16B/lane; LDS base wave-uniform, HW scatters lane i to base+i*16.
__device__ __forceinline__ void gll16(const f16* g, f16* l) {
  __builtin_amdgcn_global_load_lds(
      (const __attribute__((address_space(1))) void*)g,
      (__attribute__((address_space(3))) void*)l, 16, 0, 0);
}

// 128 x (FJ*32) tile GEMM step (validated round 5): A split at k=512 between two
// sources, W [N][K] k-contiguous, bias+tanh epilogue via LDS transpose, out stride 512.
template<int FJ>
__device__ __forceinline__ void tile_gemm(
    const f16* __restrict__ A0, int ldA0,   // k in [0,512)
    const f16* __restrict__ A1, int ldA1,   // k in [512,K), col index k-512
    int K, const f16* __restrict__ WT,
    const float* __restrict__ bias,
    f16* __restrict__ outp, int bm, int bn, f16* sm)
{
  const int tid  = threadIdx.x;
  const int w    = tid >> 6;
  const int lane = tid & 63;
  const int lm   = lane & 15;
  const int quad = lane >> 4;
  const int wm   = (w >> 1) * 64;
  const int wn   = (w & 1) * (FJ * 16);
  const int srow8 = lane >> 3;
  const int scol  = (lane & 7) * 8;

  f16* As0 = sm;
  f16* Ws0 = sm + 128 * 64;

  floatx4 acc[4][FJ];
  #pragma unroll
  for (int i = 0; i < 4; ++i)
    #pragma unroll
    for (int j = 0; j < FJ; ++j)
      acc[i][j] = (floatx4){0.f, 0.f, 0.f, 0.f};

  for (int k0 = 0; k0 < K; k0 += 64) {
    const f16* Asrc = (k0 < 512) ? (A0 + k0) : (A1 + (k0 - 512));
    const int  ld   = (k0 < 512) ? ldA0 : ldA1;
    #pragma unroll
    for (int i = 0; i < 4; ++i) {
      int r = (w * 4 + i) * 8 + srow8;
      gll16(Asrc + (size_t)(bm + r) * ld + scol, As0 + (w * 4 + i) * 512);
    }
    #pragma unroll
    for (int i = 0; i < FJ; ++i) {
      int r = (w * FJ + i) * 8 + srow8;
      gll16(WT + (size_t)(bn + r) * K + k0 + scol, Ws0 + (w * FJ + i) * 512);
    }
    __syncthreads();
    #pragma unroll
    for (int kk = 0; kk < 64; kk += 32) {
      f16x8 a[4], bfr[FJ];
      #pragma unroll
      for (int fi = 0; fi < 4; ++fi)
        a[fi] = *(const f16x8*)&As0[(size_t)(wm + fi * 16 + lm) * 64 + kk + quad * 8];
      #pragma unroll
      for (int fj = 0; fj < FJ; ++fj)
        bfr[fj] = *(const f16x8*)&Ws0[(size_t)(wn + fj * 16 + lm) * 64 + kk + quad * 8];
      #pragma unroll
      for (int fi = 0; fi < 4; ++fi)
        #pragma unroll
        for (int fj = 0; fj < FJ; ++fj)
          acc[fi][fj] = __builtin_amdgcn_mfma_f32_16x16x32_f16(a[fi], bfr[fj], acc[fi][fj], 0, 0, 0);
    }
    __syncthreads();
  }

  // epilogue: C/D layout col=lane&15, row=quad*4+reg [m89/m91] -> LDS transpose
  constexpr int ES = FJ * 32 + 8;
  #pragma unroll
  for (int fi = 0; fi < 4; ++fi)
    #pragma unroll
    for (int fj = 0; fj < FJ; ++fj) {
      int col = wn + fj * 16 + lm;
      #pragma unroll
      for (int r = 0; r < 4; ++r) {
        int row = wm + fi * 16 + quad * 4 + r;
        sm[row * ES + col] = (f16)acc[fi][fj][r];
      }
    }
  __syncthreads();
  constexpr int TPR = (FJ * 32) / 8;     // threads per row
  constexpr int RPP = 256 / TPR;         // rows per pass
  #pragma unroll
  for (int p = 0; p < 128 / RPP; ++p) {
    int row = p * RPP + tid / TPR;
    int c8  = (tid % TPR) * 8;
    f16x8 ve = *(const f16x8*)&sm[row * ES + c8];
    floatx4 bv0 = *(const floatx4*)&bias[bn + c8];
    floatx4 bv1 = *(const floatx4*)&bias[bn + c8 + 4];
    union { f16 e[8]; f16x8 v; } o;
    #pragma unroll
    for (int j = 0; j < 4; ++j) o.e[j]     = (f16)ftanh((float)ve[j]     + bv0[j]);
    #pragma unroll
    for (int j = 0; j < 4; ++j) o.e[4 + j] = (f16)ftanh((float)ve[4 + j] + bv1[j]);
    *(f16x8*)(outp + (size_t)(bm + row) * 512 + bn + c8) = o.v;
  }
}

// One anti-diagonal wavefront: 512 blocks, 2/CU, balanced (each CU: one z0 +
// one z1/z2 block). slab<->XCD fixed across layers/wavefronts (b&7 heuristic)
// so H tiles stay in the home XCD's L2/L3. Kernel boundary = coherence (no
// in-kernel device fences — round-5 lesson: those cost a full L2 wb+inv each).
__global__ __launch_bounds__(256, 2)
void rnn_step(int wv, const f16* __restrict__ xh,
              const f16* __restrict__ W0T, const f16* __restrict__ W1T,
              const f16* __restrict__ W2T,
              const float* __restrict__ bcomb, const float* __restrict__ b1,
              const float* __restrict__ b2,
              const f16* __restrict__ H0c, f16* __restrict__ H0n,
              const f16* __restrict__ H1c, f16* __restrict__ H1n,
              const f16* __restrict__ H2c, f16* __restrict__ H2n)
{
  __shared__ f16 sm[17408];   // 34816 B: staging 32 KB (FJ=4) / epi 128x136
  const int b   = blockIdx.x;
  const int xcd = b & 7;
  const int r   = b >> 3;     // 0..63

  if (r < 32) {               // z0: 256 blocks, tile 128x64, K=832
    if (wv > 19) return;
    const int slab = xcd * 4 + (r & 3);
    const int bn   = (r >> 2) * 64;
    tile_gemm<2>(H0c, 512, xh + (size_t)wv * 320, 6400, 832, W0T, bcomb,
                 H0n, slab * 128, bn, sm);
  } else if (r < 48) {        // z1: 128 blocks, tile 128x128, K=1024
    if (wv < 1 || wv > 20) return;
    const int rr   = r - 32;
    const int slab = xcd * 4 + (rr & 3);
    const int bn   = (rr >> 2) * 128;
    tile_gemm<4>(H0c, 512, H1c, 512, 1024, W1T, b1, H1n, slab * 128, bn, sm);
  } else {                    // z2: 128 blocks, tile 128x128, K=1024
    if (wv < 2) return;
    const int rr   = r - 48;
    const int slab = xcd * 4 + (rr & 3);
    const int bn   = (rr >> 2) * 128;
    tile_gemm<4>(H1c, 512, H2c, 512, 1024, W2T, b2, H2n, slab * 128, bn, sm);
  }
}

// x [81920][300] fp32 -> xh [81920][320] f16 (zero-padded).
// 81920 rows x 40 f16x8-chunks = 3,276,800 chunks -> 12800 blocks x 256 threads.
// (Round-6 bug: launched 1600 blocks = 1/8 coverage, rest stayed 0xAA poison.)
__global__ void xh_conv(const float* __restrict__ x, f16* __restrict__ xh)
{
  int U = blockIdx.x * 256 + threadIdx.x;   // 0 .. 3,276,799
  int row = U / 40;
  int c   = (U - row * 40) * 8;
  union { f16 e[8]; f16x8 v; } t;
  const float* src = x + (size_t)row * 300 + c;
  if (c + 8 <= 300) {
    floatx4 v0 = *(const floatx4*)src, v1 = *(const floatx4*)(src + 4);
    #pragma unroll
    for (int j = 0; j < 4; ++j) { t.e[j] = (f16)v0[j]; t.e[4 + j] = (f16)v1[j]; }
  } else if (c < 300) {   // c == 296: 4 real + 4 pad
    floatx4 v0 = *(const floatx4*)src;
    #pragma unroll
    for (int j = 0; j < 4; ++j) { t.e[j] = (f16)v0[j]; t.e[4 + j] = (f16)0.f; }
  } else {
    #pragma unroll
    for (int j = 0; j < 8; ++j) t.e[j] = (f16)0.f;
  }
  *(f16x8*)(xh + (size_t)row * 320 + c) = t.v;
}

// Wce = W_emb @ wx0 into W0T[:, 512+k] (row stride 832); bcomb = b0 + b_emb@wx0
__global__ void prep_wce(const float* __restrict__ W_emb, const float* __restrict__ wx0,
                         const float* __restrict__ b_emb, const float* __restrict__ b0,
                         f16* __restrict__ W0T, float* __restrict__ bcomb)
{
  int id = blockIdx.x * 256 + threadIdx.x;   // 163840 exactly
  int n = id & 511;
  int k = id >> 9;                            // 0..319
  float s = 0.f;
  if (k < 300) {
    #pragma unroll 4
    for (int j = 0; j < 512; ++j)
      s = __builtin_fmaf(W_emb[k * 512 + j], wx0[j * 512 + n], s);
  }
  W0T[(size_t)n * 832 + 512 + k] = (f16)s;
  if (id < 512) {
    float sb = b0[id];
    for (int j = 0; j < 512; ++j)
      sb = __builtin_fmaf(b_emb[j], wx0[j * 512 + id], sb);
    bcomb[id] = sb;
  }
}

// Transposes: wh0 -> W0T[:, :512] (stride 832); [wx1;wh1] -> W1T; [wx2;wh2] -> W2T
__global__ void prep_wt(const float* __restrict__ wh0,
                        const float* __restrict__ wx1, const float* __restrict__ wh1,
                        const float* __restrict__ wx2, const float* __restrict__ wh2,
                        f16* __restrict__ W0T, f16* __restrict__ W1T, f16* __restrict__ W2T)
{
  int id = blockIdx.x * 256 + threadIdx.x;   // 1310720 exactly
  if (id < 262144) {
    int n = id & 511, k = id >> 9;
    W0T[(size_t)n * 832 + k] = (f16)wh0[k * 512 + n];
  } else if (id < 786432) {
    int i2 = id - 262144;
    int n = i2 & 511, k = i2 >> 9;           // 0..1023
    float v = (k < 512) ? wx1[k * 512 + n] : wh1[(k - 512) * 512 + n];
    W1T[(size_t)n * 1024 + k] = (f16)v;
  } else {
    int i2 = id - 786432;
    int n = i2 & 511, k = i2 >> 9;
    float v = (k < 512) ? wx2[k * 512 + n] : wh2[(k - 512) * 512 + n];
    W2T[(size_t)n * 1024 + k] = (f16)v;
  }
}

// out[4096,10] = h2[4096,512](f16) @ W_fc[512,10] + b_fc
__global__ void fc_kernel(const f16* __restrict__ h2,
                          const float* __restrict__ Wfc, const float* __restrict__ bfc,
                          float* __restrict__ out)
{
  int id = blockIdx.x * 256 + threadIdx.x;   // 40960 exactly
  int row = id / 10;
  int c = id - row * 10;
  float s = bfc[c];
  const f16* hr = h2 + (size_t)row * 512;
  for (int k8 = 0; k8 < 64; ++k8) {
    f16x8 h8 = *(const f16x8*)(hr + k8 * 8);
    #pragma unroll
    for (int j = 0; j < 8; ++j)
      s = __builtin_fmaf((float)h8[j], Wfc[(k8 * 8 + j) * 10 + c], s);
  }
  out[id] = s;
}

extern "C" void kernel_launch(void* const* d_in, const int* in_sizes, int n_in,
                              void* d_out, int out_size, void* d_ws, size_t ws_size,
                              hipStream_t stream)
{
  (void)in_sizes; (void)n_in; (void)out_size; (void)ws_size;
  const float* x     = (const float*)d_in[0];
  const float* W_emb = (const float*)d_in[1];
  const float* b_emb = (const float*)d_in[2];
  const float* wx0   = (const float*)d_in[3];
  const float* wh0   = (const float*)d_in[4];
  const float* b0    = (const float*)d_in[5];
  const float* wx1   = (const float*)d_in[6];
  const float* wh1   = (const float*)d_in[7];
  const float* b1    = (const float*)d_in[8];
  const float* wx2   = (const float*)d_in[9];
  const float* wh2   = (const float*)d_in[10];
  const float* b2    = (const float*)d_in[11];
  const float* W_fc  = (const float*)d_in[12];
  const float* b_fc  = (const float*)d_in[13];
  float* out = (float*)d_out;

  char* ws = (char*)d_ws;
  size_t off = 0;
  auto alloc = [&](size_t bytes) -> void* {
    void* p = ws + off;
    off = (off + bytes + 255) & ~(size_t)255;
    return p;
  };
  f16*   xh    = (f16*)alloc((size_t)81920 * 320 * 2);   // 52.4 MB
  f16*   W0T   = (f16*)alloc((size_t)512 * 832 * 2);
  f16*   W1T   = (f16*)alloc((size_t)512 * 1024 * 2);
  f16*   W2T   = (f16*)alloc((size_t)512 * 1024 * 2);
  float* bcomb = (float*)alloc(512 * 4);
  f16*   H0a   = (f16*)alloc((size_t)4096 * 512 * 2);
  f16*   H0b   = (f16*)alloc((size_t)4096 * 512 * 2);
  f16*   H1a   = (f16*)alloc((size_t)4096 * 512 * 2);
  f16*   H1b   = (f16*)alloc((size_t)4096 * 512 * 2);
  f16*   H2a   = (f16*)alloc((size_t)4096 * 512 * 2);
  f16*   H2b   = (f16*)alloc((size_t)4096 * 512 * 2);

  // prep (parallel, independent)
  xh_conv<<<12800, 256, 0, stream>>>(x, xh);
  prep_wce<<<640, 256, 0, stream>>>(W_emb, wx0, b_emb, b0, W0T, bcomb);
  prep_wt<<<5120, 256, 0, stream>>>(wh0, wx1, wh1, wx2, wh2, W0T, W1T, W2T);

  // zero-init: h0(-1)=H0a (read wv=0), h1(-1)=H1b (read wv=1), h2(-1)=H2a (read wv=2)
  hipMemsetAsync(H0a, 0, (size_t)4096 * 512 * 2, stream);
  hipMemsetAsync(H1b, 0, (size_t)4096 * 512 * 2, stream);
  hipMemsetAsync(H2a, 0, (size_t)4096 * 512 * 2, stream);

  // 22 anti-diagonal wavefronts: z0(t=wv), z1(t=wv-1), z2(t=wv-2)
  for (int wv = 0; wv < 22; ++wv) {
    const int cur = wv & 1;
    f16* H0c = cur ? H0b : H0a;  f16* H0n = cur ? H0a : H0b;
    f16* H1c = cur ? H1b : H1a;  f16* H1n = cur ? H1a : H1b;
    f16* H2c = cur ? H2b : H2a;  f16* H2n = cur ? H2a : H2b;
    rnn_step<<<512, 256, 0, stream>>>(wv, xh, W0T, W1T, W2T, bcomb, b1, b2,
                                      H0c, H0n, H1c, H1n, H2c, H2n);
  }

  // h2(19) written at wv=21 into H2n(cur=1) = H2a
  fc_kernel<<<160, 256, 0, stream>>>(H2a, W_fc, b_fc, out);
}

// Round 8
// 816.398 us; speedup vs baseline: 2.2466x; 1.0500x over previous
//
#include <hip/hip_runtime.h>

typedef _Float16 f16;
typedef _Float16 f16x8 __attribute__((ext_vector_type(8)));
typedef float floatx4 __attribute__((ext_vector_type(4)));

__device__ __forceinline__ float ftanh(float x) {
  float ax = __builtin_fabsf(x);
  float e  = __expf(-2.0f * ax);
  float t  = (1.0f - e) * __builtin_amdgcn_rcpf(1.0f + e);
  return x < 0.0f ? -t : t;
}

// async global->LDS, 16B/lane; LDS base wave-uniform, HW scatters lane i to base+i*16.
__device__ __forceinline__ void gll16(const f16* g, f16* l) {
  __builtin_amdgcn_global_load_lds(
      (const __attribute__((address_space(1))) void*)g,
      (__attribute__((address_space(3))) void*)l, 16, 0, 0);
}

// 128 x (FJ*32) tile GEMM step (validated round 5/7): A split at k=512 between two
// sources, W [N][K] k-contiguous, bias+tanh epilogue via LDS transpose, out stride 512.
template<int FJ>
__device__ __forceinline__ void tile_gemm(
    const f16* __restrict__ A0, int ldA0,   // k in [0,512)
    const f16* __restrict__ A1, int ldA1,   // k in [512,K), col index k-512
    int K, const f16* __restrict__ WT,
    const float* __restrict__ bias,
    f16* __restrict__ outp, int bm, int bn, f16* sm)
{
  const int tid  = threadIdx.x;
  const int w    = tid >> 6;
  const int lane = tid & 63;
  const int lm   = lane & 15;
  const int quad = lane >> 4;
  const int wm   = (w >> 1) * 64;
  const int wn   = (w & 1) * (FJ * 16);
  const int srow8 = lane >> 3;
  const int scol  = (lane & 7) * 8;

  f16* As0 = sm;
  f16* Ws0 = sm + 128 * 64;

  floatx4 acc[4][FJ];
  #pragma unroll
  for (int i = 0; i < 4; ++i)
    #pragma unroll
    for (int j = 0; j < FJ; ++j)
      acc[i][j] = (floatx4){0.f, 0.f, 0.f, 0.f};

  for (int k0 = 0; k0 < K; k0 += 64) {
    const f16* Asrc = (k0 < 512) ? (A0 + k0) : (A1 + (k0 - 512));
    const int  ld   = (k0 < 512) ? ldA0 : ldA1;
    #pragma unroll
    for (int i = 0; i < 4; ++i) {
      int r = (w * 4 + i) * 8 + srow8;
      gll16(Asrc + (size_t)(bm + r) * ld + scol, As0 + (w * 4 + i) * 512);
    }
    #pragma unroll
    for (int i = 0; i < FJ; ++i) {
      int r = (w * FJ + i) * 8 + srow8;
      gll16(WT + (size_t)(bn + r) * K + k0 + scol, Ws0 + (w * FJ + i) * 512);
    }
    __syncthreads();
    #pragma unroll
    for (int kk = 0; kk < 64; kk += 32) {
      f16x8 a[4], bfr[FJ];
      #pragma unroll
      for (int fi = 0; fi < 4; ++fi)
        a[fi] = *(const f16x8*)&As0[(size_t)(wm + fi * 16 + lm) * 64 + kk + quad * 8];
      #pragma unroll
      for (int fj = 0; fj < FJ; ++fj)
        bfr[fj] = *(const f16x8*)&Ws0[(size_t)(wn + fj * 16 + lm) * 64 + kk + quad * 8];
      #pragma unroll
      for (int fi = 0; fi < 4; ++fi)
        #pragma unroll
        for (int fj = 0; fj < FJ; ++fj)
          acc[fi][fj] = __builtin_amdgcn_mfma_f32_16x16x32_f16(a[fi], bfr[fj], acc[fi][fj], 0, 0, 0);
    }
    __syncthreads();
  }

  // epilogue: C/D layout col=lane&15, row=quad*4+reg [m89/m91] -> LDS transpose
  constexpr int ES = FJ * 32 + 8;
  #pragma unroll
  for (int fi = 0; fi < 4; ++fi)
    #pragma unroll
    for (int fj = 0; fj < FJ; ++fj) {
      int col = wn + fj * 16 + lm;
      #pragma unroll
      for (int r = 0; r < 4; ++r) {
        int row = wm + fi * 16 + quad * 4 + r;
        sm[row * ES + col] = (f16)acc[fi][fj][r];
      }
    }
  __syncthreads();
  constexpr int TPR = (FJ * 32) / 8;     // threads per row
  constexpr int RPP = 256 / TPR;         // rows per pass
  #pragma unroll
  for (int p = 0; p < 128 / RPP; ++p) {
    int row = p * RPP + tid / TPR;
    int c8  = (tid % TPR) * 8;
    f16x8 ve = *(const f16x8*)&sm[row * ES + c8];
    floatx4 bv0 = *(const floatx4*)&bias[bn + c8];
    floatx4 bv1 = *(const floatx4*)&bias[bn + c8 + 4];
    union { f16 e[8]; f16x8 v; } o;
    #pragma unroll
    for (int j = 0; j < 4; ++j) o.e[j]     = (f16)ftanh((float)ve[j]     + bv0[j]);
    #pragma unroll
    for (int j = 0; j < 4; ++j) o.e[4 + j] = (f16)ftanh((float)ve[4 + j] + bv1[j]);
    *(f16x8*)(outp + (size_t)(bm + row) * 512 + bn + c8) = o.v;
  }
}

// One anti-diagonal wavefront: 512 blocks, 2/CU, balanced. slab<->XCD fixed
// across layers/wavefronts so H tiles stay in the home XCD's L2/L3.
__global__ __launch_bounds__(256, 2)
void rnn_step(int wv, const f16* __restrict__ xh,
              const f16* __restrict__ W0T, const f16* __restrict__ W1T,
              const f16* __restrict__ W2T,
              const float* __restrict__ bcomb, const float* __restrict__ b1,
              const float* __restrict__ b2,
              const f16* __restrict__ H0c, f16* __restrict__ H0n,
              const f16* __restrict__ H1c, f16* __restrict__ H1n,
              const f16* __restrict__ H2c, f16* __restrict__ H2n)
{
  __shared__ f16 sm[17408];   // 34816 B: staging 32 KB (FJ=4) / epi 128x136
  const int b   = blockIdx.x;
  const int xcd = b & 7;
  const int r   = b >> 3;     // 0..63

  if (r < 32) {               // z0: 256 blocks, tile 128x64, K=832
    if (wv > 19) return;
    const int slab = xcd * 4 + (r & 3);
    const int bn   = (r >> 2) * 64;
    tile_gemm<2>(H0c, 512, xh + (size_t)wv * 320, 6400, 832, W0T, bcomb,
                 H0n, slab * 128, bn, sm);
  } else if (r < 48) {        // z1: 128 blocks, tile 128x128, K=1024
    if (wv < 1 || wv > 20) return;
    const int rr   = r - 32;
    const int slab = xcd * 4 + (rr & 3);
    const int bn   = (rr >> 2) * 128;
    tile_gemm<4>(H0c, 512, H1c, 512, 1024, W1T, b1, H1n, slab * 128, bn, sm);
  } else {                    // z2: 128 blocks, tile 128x128, K=1024
    if (wv < 2) return;
    const int rr   = r - 48;
    const int slab = xcd * 4 + (rr & 3);
    const int bn   = (rr >> 2) * 128;
    tile_gemm<4>(H1c, 512, H2c, 512, 1024, W2T, b2, H2n, slab * 128, bn, sm);
  }
}

// ---------------------------------------------------------------------------
// Fused prep: one dispatch, block-range roles (round-7 lesson: same-stream
// prep kernels serialize; prep_wce's 512-long serial FMA chain was 82 us).
//   [0,12800)        : x fp32 -> xh f16 (zero-padded to 320)
//   [12800,15361)    : Wce = W_emb @ wx0 (split-K x4, LDS reduce) + bcomb
//   [15361,20481)    : weight transposes -> W0T/W1T/W2T
//   [20481,23553)    : zero-init H0a, H1b, H2a
// ---------------------------------------------------------------------------
#define XH_END  12800
#define WCE_END 15361
#define WT_END  20481
#define Z_END   23553

__global__ __launch_bounds__(256)
void prep_all(const float* __restrict__ x,
              const float* __restrict__ W_emb, const float* __restrict__ b_emb,
              const float* __restrict__ wx0, const float* __restrict__ wh0,
              const float* __restrict__ b0,
              const float* __restrict__ wx1, const float* __restrict__ wh1,
              const float* __restrict__ wx2, const float* __restrict__ wh2,
              f16* __restrict__ xh, f16* __restrict__ W0T,
              f16* __restrict__ W1T, f16* __restrict__ W2T,
              float* __restrict__ bcomb,
              f16* __restrict__ H0a, f16* __restrict__ H1b, f16* __restrict__ H2a)
{
  __shared__ float red[256];
  const int b   = blockIdx.x;
  const int tid = threadIdx.x;

  if (b < XH_END) {
    // 12800*256 = 3,276,800 chunks: one f16x8 per thread
    int U   = b * 256 + tid;
    int row = U / 40;
    int c   = (U - row * 40) * 8;
    union { f16 e[8]; f16x8 v; } t;
    const float* src = x + (size_t)row * 300 + c;
    if (c + 8 <= 300) {
      floatx4 v0 = *(const floatx4*)src, v1 = *(const floatx4*)(src + 4);
      #pragma unroll
      for (int j = 0; j < 4; ++j) { t.e[j] = (f16)v0[j]; t.e[4 + j] = (f16)v1[j]; }
    } else if (c < 300) {   // c == 296: 4 real + 4 pad
      floatx4 v0 = *(const floatx4*)src;
      #pragma unroll
      for (int j = 0; j < 4; ++j) { t.e[j] = (f16)v0[j]; t.e[4 + j] = (f16)0.f; }
    } else {
      #pragma unroll
      for (int j = 0; j < 8; ++j) t.e[j] = (f16)0.f;
    }
    *(f16x8*)(xh + (size_t)row * 320 + c) = t.v;
  } else if (b < WCE_END) {
    int bb = b - XH_END;
    if (bb < 2560) {
      // Wce[k][n] = sum_j W_emb[k][j]*wx0[j][n]; 64 outputs x 4 j-chunks per block
      int oidx  = bb * 64 + (tid & 63);     // 0..163839
      int chunk = tid >> 6;                  // 0..3
      int n = oidx & 511, k = oidx >> 9;     // k 0..319
      float s = 0.f;
      if (k < 300) {
        const float* we = W_emb + k * 512 + chunk * 128;
        const float* wx = wx0 + (size_t)(chunk * 128) * 512 + n;
        #pragma unroll 4
        for (int j = 0; j < 128; ++j)
          s = __builtin_fmaf(we[j], wx[(size_t)j * 512], s);
      }
      red[tid] = s;
      __syncthreads();
      if (chunk == 0)
        W0T[(size_t)n * 832 + 512 + k] =
            (f16)(red[tid] + red[tid + 64] + red[tid + 128] + red[tid + 192]);
    } else {
      // bcomb = b0 + b_emb @ wx0 (512 outputs, 2 per thread)
      #pragma unroll
      for (int p = 0; p < 2; ++p) {
        int n = p * 256 + tid;
        float s = b0[n];
        for (int j = 0; j < 512; ++j)
          s = __builtin_fmaf(b_emb[j], wx0[(size_t)j * 512 + n], s);
        bcomb[n] = s;
      }
    }
  } else if (b < WT_END) {
    // transposes: 5120*256 = 1,310,720 elements
    int id = (b - WCE_END) * 256 + tid;
    if (id < 262144) {
      int n = id & 511, k = id >> 9;
      W0T[(size_t)n * 832 + k] = (f16)wh0[k * 512 + n];
    } else if (id < 786432) {
      int i2 = id - 262144;
      int n = i2 & 511, k = i2 >> 9;         // 0..1023
      float v = (k < 512) ? wx1[k * 512 + n] : wh1[(k - 512) * 512 + n];
      W1T[(size_t)n * 1024 + k] = (f16)v;
    } else {
      int i2 = id - 786432;
      int n = i2 & 511, k = i2 >> 9;
      float v = (k < 512) ? wx2[k * 512 + n] : wh2[(k - 512) * 512 + n];
      W2T[(size_t)n * 1024 + k] = (f16)v;
    }
  } else {
    // zero-init h(-1): H0a, H1b, H2a — 3072*256 = 786,432 f16x8 chunks
    int id = (b - WT_END) * 256 + tid;
    f16x8 z8 = {};
    f16* dst = (id < 262144) ? H0a : (id < 524288) ? H1b : H2a;
    *(f16x8*)(dst + (size_t)(id & 262143) * 8) = z8;
  }
}

// out[4096,10] = h2[4096,512](f16) @ W_fc[512,10] + b_fc
__global__ void fc_kernel(const f16* __restrict__ h2,
                          const float* __restrict__ Wfc, const float* __restrict__ bfc,
                          float* __restrict__ out)
{
  int id = blockIdx.x * 256 + threadIdx.x;   // 40960 exactly
  int row = id / 10;
  int c = id - row * 10;
  float s = bfc[c];
  const f16* hr = h2 + (size_t)row * 512;
  for (int k8 = 0; k8 < 64; ++k8) {
    f16x8 h8 = *(const f16x8*)(hr + k8 * 8);
    #pragma unroll
    for (int j = 0; j < 8; ++j)
      s = __builtin_fmaf((float)h8[j], Wfc[(k8 * 8 + j) * 10 + c], s);
  }
  out[id] = s;
}

extern "C" void kernel_launch(void* const* d_in, const int* in_sizes, int n_in,
                              void* d_out, int out_size, void* d_ws, size_t ws_size,
                              hipStream_t stream)
{
  (void)in_sizes; (void)n_in; (void)out_size; (void)ws_size;
  const float* x     = (const float*)d_in[0];
  const float* W_emb = (const float*)d_in[1];
  const float* b_emb = (const float*)d_in[2];
  const float* wx0   = (const float*)d_in[3];
  const float* wh0   = (const float*)d_in[4];
  const float* b0    = (const float*)d_in[5];
  const float* wx1   = (const float*)d_in[6];
  const float* wh1   = (const float*)d_in[7];
  const float* b1    = (const float*)d_in[8];
  const float* wx2   = (const float*)d_in[9];
  const float* wh2   = (const float*)d_in[10];
  const float* b2    = (const float*)d_in[11];
  const float* W_fc  = (const float*)d_in[12];
  const float* b_fc  = (const float*)d_in[13];
  float* out = (float*)d_out;

  char* ws = (char*)d_ws;
  size_t off = 0;
  auto alloc = [&](size_t bytes) -> void* {
    void* p = ws + off;
    off = (off + bytes + 255) & ~(size_t)255;
    return p;
  };
  f16*   xh    = (f16*)alloc((size_t)81920 * 320 * 2);   // 52.4 MB
  f16*   W0T   = (f16*)alloc((size_t)512 * 832 * 2);
  f16*   W1T   = (f16*)alloc((size_t)512 * 1024 * 2);
  f16*   W2T   = (f16*)alloc((size_t)512 * 1024 * 2);
  float* bcomb = (float*)alloc(512 * 4);
  f16*   H0a   = (f16*)alloc((size_t)4096 * 512 * 2);
  f16*   H0b   = (f16*)alloc((size_t)4096 * 512 * 2);
  f16*   H1a   = (f16*)alloc((size_t)4096 * 512 * 2);
  f16*   H1b   = (f16*)alloc((size_t)4096 * 512 * 2);
  f16*   H2a   = (f16*)alloc((size_t)4096 * 512 * 2);
  f16*   H2b   = (f16*)alloc((size_t)4096 * 512 * 2);

  // one fused prep dispatch (xh + Wce + bcomb + transposes + H zero-init)
  prep_all<<<Z_END, 256, 0, stream>>>(x, W_emb, b_emb, wx0, wh0, b0,
                                      wx1, wh1, wx2, wh2,
                                      xh, W0T, W1T, W2T, bcomb, H0a, H1b, H2a);

  // 22 anti-diagonal wavefronts: z0(t=wv), z1(t=wv-1), z2(t=wv-2)
  for (int wv = 0; wv < 22; ++wv) {
    const int cur = wv & 1;
    f16* H0c = cur ? H0b : H0a;  f16* H0n = cur ? H0a : H0b;
    f16* H1c = cur ? H1b : H1a;  f16* H1n = cur ? H1a : H1b;
    f16* H2c = cur ? H2b : H2a;  f16* H2n = cur ? H2a : H2b;
    rnn_step<<<512, 256, 0, stream>>>(wv, xh, W0T, W1T, W2T, bcomb, b1, b2,
                                      H0c, H0n, H1c, H1n, H2c, H2n);
  }

  // h2(19) written at wv=21 into H2n(cur=1) = H2a
  fc_kernel<<<160, 256, 0, stream>>>(H2a, W_fc, b_fc, out);
}